// Round 1
// baseline (1015.151 us; speedup 1.0000x reference)
//
#include <hip/hip_runtime.h>

// ---------------------------------------------------------------------------
// SSM (Mamba2-style) fused forward for MI355X.
// Pipeline:
//   cast x,W_in -> bf16 ; GEMM1 (bf16 MFMA) -> zxbcdt(bf16, stride 8576)
//   conv+silu -> xBCc(bf16) ; dt prep (softplus/clip, chunk cumsum)
//   CB = C.B^T per chunk ; intra (masked decay einsum) ; states GEMM ;
//   chunk recurrence ; inter ; gate+RMSNorm -> yb(bf16) ; GEMM2 -> d_out(f32)
// ws layout (bytes):
//   xb      @0          16,777,216   (dead after GEMM1)
//   winb    @16,777,216 35,127,296   (dead after GEMM1)
//   yb      @0          33,554,432   (alias; written at gate)
//   woutb   @33,554,432 16,777,216   (alias; cast after GEMM1)
//   zx      @51,904,512 70,254,592   4096x8576 bf16
//   xbcc    @122,159,104 35,651,584  4096x4352 bf16
//   dtp     @157,810,688 524,288     [b][H][s] f32
//   dacs    @158,334,976 524,288     [b][H][s] f32 (per-256-chunk cumsum)
//   cb      @158,859,264 4,194,304   [b*nc][256][256] f32
//   yf      @163,053,568 67,108,864  4096x4096 f32
//   st      @230,162,432 33,554,432  [b][c][h][p][n] f32 (states -> prev)
//   TOTAL 263,716,864 bytes
// ---------------------------------------------------------------------------

typedef short s16x8 __attribute__((ext_vector_type(8)));
typedef float f32x4 __attribute__((ext_vector_type(4)));

__device__ __forceinline__ float bf2f(ushort u) {
    return __builtin_bit_cast(float, (unsigned)u << 16);
}
__device__ __forceinline__ ushort f2bf(float f) {
    unsigned u = __builtin_bit_cast(unsigned, f);
    unsigned r = u + 0x7fffu + ((u >> 16) & 1u);
    return (ushort)(r >> 16);
}

__device__ __forceinline__ void gld16(const void* g, void* l) {
    __builtin_amdgcn_global_load_lds((__attribute__((address_space(1))) void*)g,
                                     (__attribute__((address_space(3))) void*)l, 16, 0, 0);
}

// ---------------- cast kernels ----------------
__global__ void cast4_k(const float4* __restrict__ in, ushort* __restrict__ out, long n4) {
    long i = (long)blockIdx.x * blockDim.x + threadIdx.x;
    if (i >= n4) return;
    float4 v = in[i];
    ushort4 o = { f2bf(v.x), f2bf(v.y), f2bf(v.z), f2bf(v.w) };
    *(ushort4*)(out + i * 4) = o;
}

__global__ void cast_win_k(const float4* __restrict__ in, ushort* __restrict__ out) {
    long i = (long)blockIdx.x * blockDim.x + threadIdx.x;  // n4 = 8576*2048/4
    if (i >= (long)8576 * 2048 / 4) return;
    ushort4 o;
    if (i < (long)8480 * 2048 / 4) {
        float4 v = in[i];
        o = { f2bf(v.x), f2bf(v.y), f2bf(v.z), f2bf(v.w) };
    } else {
        o = { 0, 0, 0, 0 };
    }
    *(ushort4*)(out + i * 4) = o;
}

// ---------------- bf16 MFMA GEMM: C[M,N] = A[M,K] * B[N,K]^T ----------------
// 128x128 tile, BK=32, 256 threads (4 waves 2x2), per-wave 64x64 (4x4 frags).
template <int OUTBF>
__global__ __launch_bounds__(256) void gemm_bt_k(const ushort* __restrict__ A,
                                                 const ushort* __restrict__ Bm,
                                                 void* __restrict__ Cout,
                                                 int M, int Ncols, int Kd) {
    __shared__ ushort As[128 * 32];
    __shared__ ushort Bs[128 * 32];
    const int tid = threadIdx.x;
    const int lane = tid & 63, wave = tid >> 6;
    const int wm = wave >> 1, wn = wave & 1;
    const long m0 = (long)blockIdx.y * 128, n0 = (long)blockIdx.x * 128;

    f32x4 zero = { 0.f, 0.f, 0.f, 0.f };
    f32x4 acc[4][4];
#pragma unroll
    for (int i = 0; i < 4; i++)
#pragma unroll
        for (int j = 0; j < 4; j++) acc[i][j] = zero;

    const int eb = wave * 512 + lane * 8;  // bf16 element offset within 128x32 tile
    for (int kt = 0; kt < Kd; kt += 32) {
        __syncthreads();
#pragma unroll
        for (int j = 0; j < 2; j++) {
            int e = j * 2048 + eb;
            int row = e >> 5, col = e & 31;
            gld16(A + (m0 + row) * Kd + kt + col, As + e);
            gld16(Bm + (n0 + row) * Kd + kt + col, Bs + e);
        }
        asm volatile("s_waitcnt vmcnt(0)" ::: "memory");
        __syncthreads();
        s16x8 af[4], bfr[4];
        const int ra = (wm * 64 + (lane & 15)) * 32 + (lane >> 4) * 8;
        const int rb = (wn * 64 + (lane & 15)) * 32 + (lane >> 4) * 8;
#pragma unroll
        for (int i = 0; i < 4; i++) {
            af[i] = *(const s16x8*)(As + ra + i * 512);
            bfr[i] = *(const s16x8*)(Bs + rb + i * 512);
        }
#pragma unroll
        for (int mi = 0; mi < 4; mi++)
#pragma unroll
            for (int ni = 0; ni < 4; ni++)
                acc[mi][ni] = __builtin_amdgcn_mfma_f32_16x16x32_bf16(af[mi], bfr[ni], acc[mi][ni], 0, 0, 0);
    }
    const long crow = m0 + wm * 64 + ((lane >> 4) << 2);
    const long ccol = n0 + wn * 64 + (lane & 15);
#pragma unroll
    for (int mi = 0; mi < 4; mi++)
#pragma unroll
        for (int ni = 0; ni < 4; ni++)
#pragma unroll
            for (int r = 0; r < 4; r++) {
                long idx = (crow + mi * 16 + r) * (long)Ncols + ccol + ni * 16;
                if (OUTBF) ((ushort*)Cout)[idx] = f2bf(acc[mi][ni][r]);
                else       ((float*)Cout)[idx] = acc[mi][ni][r];
            }
}

// ---------------- causal conv (K=4) + SiLU ----------------
__global__ void conv_silu_k(const ushort* __restrict__ zx, const float* __restrict__ w,
                            const float* __restrict__ bias, ushort* __restrict__ out) {
    const int bx = blockIdx.x;            // grid 4096*17
    const int t = bx / 17, cg = bx % 17;
    const int c = cg * 256 + threadIdx.x; // < 4352
    const int bi = t >> 11, pos = t & 2047;
    float acc = bias[c];
#pragma unroll
    for (int k = 0; k < 4; k++) {
        int p = pos + k - 3;
        if (p >= 0) acc += bf2f(zx[((long)(bi * 2048 + p)) * 8576 + 4096 + c]) * w[c * 4 + k];
    }
    out[(long)t * 4352 + c] = f2bf(acc / (1.f + __expf(-acc)));
}

// ---------------- dt softplus/clip + per-chunk cumsum ----------------
__global__ void prep_k(const ushort* __restrict__ zx, const float* __restrict__ dt_bias,
                       const float* __restrict__ A_log, float* __restrict__ dtp,
                       float* __restrict__ dacs) {
    const int bx = blockIdx.x;  // 512 = bi(2) x cc(8) x h(32)
    const int h = bx & 31, cc = (bx >> 5) & 7, bi = bx >> 8;
    const int lane = threadIdx.x;  // 64
    const float A = -__expf(A_log[h]);
    const float bsh = dt_bias[h];
    float v[4], cs[4];
    float run = 0.f;
#pragma unroll
    for (int j = 0; j < 4; j++) {
        int pos = cc * 256 + lane * 4 + j;
        float raw = bf2f(zx[((long)(bi * 2048 + pos)) * 8576 + 8448 + h]) + bsh;
        float sp = (raw > 20.f) ? raw : log1pf(__expf(raw));
        float d = fminf(fmaxf(sp, 0.001f), 0.1f);
        v[j] = d;
        run += d * A;
        cs[j] = run;
    }
    float tot = run, pre = run;
    for (int off = 1; off < 64; off <<= 1) {
        float u = __shfl_up(pre, off, 64);
        if (lane >= off) pre += u;
    }
    float excl = pre - tot;
    const long base = ((long)(bi * 32 + h)) * 2048 + cc * 256 + lane * 4;
#pragma unroll
    for (int j = 0; j < 4; j++) { dtp[base + j] = v[j]; dacs[base + j] = excl + cs[j]; }
}

// ---------------- CB[l,s] = C[l,:].B[s,:] per chunk ----------------
__global__ __launch_bounds__(256) void cb_k(const ushort* __restrict__ xbcc, float* __restrict__ CB) {
    const int bx = blockIdx.x;  // 128 = bc(16) x lt(8)
    const int lt = bx & 7, bc = bx >> 3;
    const int bi = bc >> 3, cc = bc & 7;
    __shared__ ushort Bs[256][136];
    __shared__ ushort Cs2[32][136];
    const int tid = threadIdx.x;
    const long tbase = (long)bi * 2048 + cc * 256;
#pragma unroll
    for (int r = 0; r < 16; r++) {
        int u = tid + r * 256; int s = u >> 4, seg = u & 15;
        *(s16x8*)&Bs[s][seg * 8] = *(const s16x8*)&xbcc[(tbase + s) * 4352 + 4096 + seg * 8];
    }
#pragma unroll
    for (int r = 0; r < 2; r++) {
        int u = tid + r * 256; int s = u >> 4, seg = u & 15;
        *(s16x8*)&Cs2[s][seg * 8] = *(const s16x8*)&xbcc[(tbase + lt * 32 + s) * 4352 + 4224 + seg * 8];
    }
    __syncthreads();
    const int l = tid >> 3, sg = tid & 7;
    float acc[32];
#pragma unroll
    for (int j = 0; j < 32; j++) acc[j] = 0.f;
    for (int n = 0; n < 128; n++) {
        float cv = bf2f(Cs2[l][n]);
#pragma unroll
        for (int j = 0; j < 32; j++) acc[j] += cv * bf2f(Bs[sg + j * 8][n]);
    }
    const long obase = ((long)bc) * 65536 + (long)(lt * 32 + l) * 256 + sg;
#pragma unroll
    for (int j = 0; j < 32; j++) CB[obase + j * 8] = acc[j];
}

// ---------------- intra-chunk masked einsum + D*x ----------------
__global__ __launch_bounds__(256) void intra_k(const ushort* __restrict__ xbcc, const float* __restrict__ CB,
                                               const float* __restrict__ dtp, const float* __restrict__ dacs,
                                               const float* __restrict__ Dv, float* __restrict__ y) {
    const int bx = blockIdx.x;  // 4096 = bi(2) x cc(8) x h(32) x lt(8)
    const int lt = bx & 7, h = (bx >> 3) & 31, cc = (bx >> 8) & 7, bi = bx >> 11;
    __shared__ float dA_s[256];
    __shared__ float dt_s[256];
    __shared__ float CBt[32][33];
    __shared__ float xh[32][128];
    const int tid = threadIdx.x;
    const long dbase = ((long)(bi * 32 + h)) * 2048 + cc * 256;
    dA_s[tid] = dacs[dbase + tid];
    dt_s[tid] = dtp[dbase + tid];
    const int l_loc = tid >> 3, pg = tid & 7;
    const int l = lt * 32 + l_loc;
    const long tbase = (long)bi * 2048 + cc * 256;
    const long cbbase = ((long)(bi * 8 + cc)) * 65536;
    float acc[16];
#pragma unroll
    for (int j = 0; j < 16; j++) acc[j] = 0.f;

    for (int st = 0; st <= lt; st++) {
        __syncthreads();
        {
            const int ll = tid >> 3, s4 = (tid & 7) * 4;
            const float* g = &CB[cbbase + (long)(lt * 32 + ll) * 256 + st * 32 + s4];
            float4 v = *(const float4*)g;
            CBt[ll][s4 + 0] = v.x; CBt[ll][s4 + 1] = v.y;
            CBt[ll][s4 + 2] = v.z; CBt[ll][s4 + 3] = v.w;
        }
        {
            const int sr = tid >> 3, p0 = (tid & 7) * 16;
            const ushort* g = &xbcc[(tbase + st * 32 + sr) * 4352 + h * 128 + p0];
#pragma unroll
            for (int j = 0; j < 16; j++) xh[sr][p0 + j] = bf2f(g[j]);
        }
        __syncthreads();
        const float dAl = dA_s[l];
        const int smax = (st == lt) ? l_loc : 31;
        for (int ss = 0; ss <= smax; ss++) {
            const int s = st * 32 + ss;
            const float w = CBt[l_loc][ss] * __expf(dAl - dA_s[s]) * dt_s[s];
            const float* xr = &xh[ss][pg * 16];
#pragma unroll
            for (int j = 0; j < 16; j++) acc[j] += w * xr[j];
        }
    }
    const long tok = tbase + l;
    const float Dh = Dv[h];
    const ushort* xg = &xbcc[tok * 4352 + h * 128 + pg * 16];
    float* yr = &y[tok * 4096 + h * 128 + pg * 16];
#pragma unroll
    for (int j = 0; j < 16; j++) yr[j] = acc[j] + Dh * bf2f(xg[j]);
}

// ---------------- per-chunk end states ----------------
__global__ __launch_bounds__(256) void states_k(const ushort* __restrict__ xbcc, const float* __restrict__ dtp,
                                                const float* __restrict__ dacs, float* __restrict__ states) {
    const int bx = blockIdx.x;  // 2048 = bi(2) x cc(8) x h(32) x pb(4)
    const int pb = bx & 3, h = (bx >> 2) & 31, cc = (bx >> 7) & 7, bi = bx >> 10;
    __shared__ ushort Bsh[128][128];
    __shared__ ushort xsh[128][32];
    __shared__ float wl[256];
    const int tid = threadIdx.x;
    const long tbase = (long)bi * 2048 + cc * 256;
    const long dbase = ((long)(bi * 32 + h)) * 2048 + cc * 256;
    {
        float last = dacs[dbase + 255];
        wl[tid] = __expf(last - dacs[dbase + tid]) * dtp[dbase + tid];
    }
    const int pt = tid & 31, ng = tid >> 5;
    float acc[16];
#pragma unroll
    for (int j = 0; j < 16; j++) acc[j] = 0.f;
    for (int ph = 0; ph < 2; ph++) {
        __syncthreads();
#pragma unroll
        for (int r = 0; r < 8; r++) {
            int u = tid + r * 256; int s = u >> 4, seg = u & 15;
            *(s16x8*)&Bsh[s][seg * 8] = *(const s16x8*)&xbcc[(tbase + ph * 128 + s) * 4352 + 4096 + seg * 8];
        }
#pragma unroll
        for (int r = 0; r < 2; r++) {
            int u = tid + r * 256; int s = u >> 2, seg = u & 3;
            *(s16x8*)&xsh[s][seg * 8] = *(const s16x8*)&xbcc[(tbase + ph * 128 + s) * 4352 + h * 128 + pb * 32 + seg * 8];
        }
        __syncthreads();
        for (int l = 0; l < 128; l++) {
            float xv = wl[ph * 128 + l] * bf2f(xsh[l][pt]);
            const unsigned* br = (const unsigned*)&Bsh[l][ng * 16];
#pragma unroll
            for (int jj = 0; jj < 8; jj++) {
                unsigned v = br[jj];
                acc[jj * 2]     += xv * bf2f((ushort)(v & 0xffffu));
                acc[jj * 2 + 1] += xv * bf2f((ushort)(v >> 16));
            }
        }
    }
    float* out = &states[((((long)(bi * 8 + cc)) * 32 + h) * 128 + pb * 32 + pt) * 128 + ng * 16];
#pragma unroll
    for (int j = 0; j < 16; j++) out[j] = acc[j];
}

// ---------------- chunk recurrence: states -> prev_states (in place) ----------------
__global__ void rec_k(float* __restrict__ states, const float* __restrict__ dacs) {
    const int i = blockIdx.x * 256 + threadIdx.x;  // 1,048,576
    const int n = i & 127, p = (i >> 7) & 127, h = (i >> 14) & 31, bi = i >> 19;
    const long dbase = ((long)(bi * 32 + h)) * 2048;
    float run = 0.f;
    for (int cc = 0; cc < 8; cc++) {
        const long off = ((((long)(bi * 8 + cc)) * 32 + h) * 128 + p) * 128 + n;
        float st = states[off];
        states[off] = run;
        float dec = dacs[dbase + cc * 256 + 255];
        run = run * __expf(dec) + st;
    }
}

// ---------------- inter-chunk contribution ----------------
__global__ __launch_bounds__(256) void inter_k(const ushort* __restrict__ xbcc, const float* __restrict__ states,
                                               const float* __restrict__ dacs, float* __restrict__ y) {
    const int bx = blockIdx.x;  // 4096 = bi(2) x cc(8) x h(32) x lb(8)
    const int lb = bx & 7, h = (bx >> 3) & 31, cc = (bx >> 8) & 7, bi = bx >> 11;
    __shared__ float Cs[32][129];
    __shared__ ushort pT[128][132];  // prev transposed [n][p] bf16
    const int tid = threadIdx.x;
    const long tbase = (long)bi * 2048 + cc * 256;
#pragma unroll
    for (int r = 0; r < 16; r++) {
        int u = tid + r * 256; int ll = u >> 7, n = u & 127;
        Cs[ll][n] = bf2f(xbcc[(tbase + lb * 32 + ll) * 4352 + 4224 + n]);
    }
    const long sbase = ((((long)(bi * 8 + cc)) * 32 + h) * 128) * 128;
    for (int r = 0; r < 64; r++) {
        int u = r * 256 + tid; int p = u >> 7, n = u & 127;
        pT[n][p] = f2bf(states[sbase + u]);
    }
    __syncthreads();
    const int l_loc = tid >> 3, pg = tid & 7;
    float acc[16];
#pragma unroll
    for (int j = 0; j < 16; j++) acc[j] = 0.f;
    for (int n = 0; n < 128; n++) {
        float cv = Cs[l_loc][n];
        const unsigned* pr = (const unsigned*)&pT[n][pg * 16];
#pragma unroll
        for (int jj = 0; jj < 8; jj++) {
            unsigned v = pr[jj];
            acc[jj * 2]     += cv * bf2f((ushort)(v & 0xffffu));
            acc[jj * 2 + 1] += cv * bf2f((ushort)(v >> 16));
        }
    }
    const int l = lb * 32 + l_loc;
    const long tok = tbase + l;
    const float el = __expf(dacs[((long)(bi * 32 + h)) * 2048 + cc * 256 + l]);
    float* yr = &y[tok * 4096 + h * 128 + pg * 16];
#pragma unroll
    for (int j = 0; j < 16; j++) yr[j] += el * acc[j];
}

// ---------------- gate (silu(z)) + RMSNorm -> bf16 ----------------
__global__ __launch_bounds__(256) void gate_rms_k(const float* __restrict__ y, const ushort* __restrict__ zx,
                                                  const float* __restrict__ norm_w, ushort* __restrict__ yb) {
    const int t = blockIdx.x, tid = threadIdx.x;
    const float* yr = &y[(long)t * 4096];
    const ushort* zr = &zx[(long)t * 8576];
    float g[16];
    float ss = 0.f;
#pragma unroll
    for (int j = 0; j < 16; j++) {
        int i = j * 256 + tid;
        float z = bf2f(zr[i]);
        float gv = yr[i] * (z / (1.f + __expf(-z)));
        g[j] = gv;
        ss += gv * gv;
    }
#pragma unroll
    for (int off = 32; off > 0; off >>= 1) ss += __shfl_xor(ss, off, 64);
    __shared__ float red[4];
    if ((tid & 63) == 0) red[tid >> 6] = ss;
    __syncthreads();
    float tot = red[0] + red[1] + red[2] + red[3];
    float sc = rsqrtf(tot * (1.f / 4096.f) + 1e-6f);
#pragma unroll
    for (int j = 0; j < 16; j++) {
        int i = j * 256 + tid;
        yb[(long)t * 4096 + i] = f2bf(g[j] * sc * norm_w[i]);
    }
}

// ---------------------------------------------------------------------------
extern "C" void kernel_launch(void* const* d_in, const int* in_sizes, int n_in,
                              void* d_out, int out_size, void* d_ws, size_t ws_size,
                              hipStream_t stream) {
    const float* x       = (const float*)d_in[0];
    const float* W_in    = (const float*)d_in[1];
    const float* conv_w  = (const float*)d_in[2];
    const float* conv_b  = (const float*)d_in[3];
    const float* dt_bias = (const float*)d_in[4];
    const float* A_log   = (const float*)d_in[5];
    const float* Dv      = (const float*)d_in[6];
    const float* norm_w  = (const float*)d_in[7];
    const float* W_out   = (const float*)d_in[8];

    char* w8 = (char*)d_ws;
    ushort* xb    = (ushort*)(w8 + 0L);
    ushort* yb    = (ushort*)(w8 + 0L);           // alias (xb dead after GEMM1)
    ushort* winb  = (ushort*)(w8 + 16777216L);
    ushort* woutb = (ushort*)(w8 + 33554432L);    // alias (winb dead after GEMM1)
    ushort* zx    = (ushort*)(w8 + 51904512L);
    ushort* xbcc  = (ushort*)(w8 + 122159104L);
    float*  dtp   = (float*)(w8 + 157810688L);
    float*  dacs  = (float*)(w8 + 158334976L);
    float*  cb    = (float*)(w8 + 158859264L);
    float*  yf    = (float*)(w8 + 163053568L);
    float*  st    = (float*)(w8 + 230162432L);

    cast4_k<<<8192, 256, 0, stream>>>((const float4*)x, xb, 2097152L);
    cast_win_k<<<17152, 256, 0, stream>>>((const float4*)W_in, winb);
    gemm_bt_k<1><<<dim3(67, 32), 256, 0, stream>>>(xb, winb, (void*)zx, 4096, 8576, 2048);
    cast4_k<<<8192, 256, 0, stream>>>((const float4*)W_out, woutb, 2097152L);
    conv_silu_k<<<69632, 256, 0, stream>>>(zx, conv_w, conv_b, xbcc);
    prep_k<<<512, 64, 0, stream>>>(zx, dt_bias, A_log, dtp, dacs);
    cb_k<<<128, 256, 0, stream>>>(xbcc, cb);
    intra_k<<<4096, 256, 0, stream>>>(xbcc, cb, dtp, dacs, Dv, yf);
    states_k<<<2048, 256, 0, stream>>>(xbcc, dtp, dacs, st);
    rec_k<<<4096, 256, 0, stream>>>(st, dacs);
    inter_k<<<4096, 256, 0, stream>>>(xbcc, st, dacs, yf);
    gate_rms_k<<<4096, 256, 0, stream>>>(yf, zx, norm_w, yb);
    gemm_bt_k<0><<<dim3(16, 32), 256, 0, stream>>>(yb, woutb, d_out, 4096, 2048, 4096);
}

// Round 3
// 792.904 us; speedup vs baseline: 1.2803x; 1.2803x over previous
//
#include <hip/hip_runtime.h>

// ---------------------------------------------------------------------------
// SSM (Mamba2-style) fused forward for MI355X.
// R2: intra-chunk MFMA keeps in-register A (M = CB*E*F), but the B-operand
//     (X) is now staged TRANSPOSED into LDS (Xt[p][s], the m97-verified
//     [col][k] B layout) and read with plain ds_read_b128. The failed
//     ds_read_b64_tr_b16 path is removed.
// ws layout unchanged (see R0 header), TOTAL 263,716,864 bytes.
// ---------------------------------------------------------------------------

typedef short s16x8 __attribute__((ext_vector_type(8)));
typedef float f32x4 __attribute__((ext_vector_type(4)));

__device__ __forceinline__ float bf2f(ushort u) {
    return __builtin_bit_cast(float, (unsigned)u << 16);
}
__device__ __forceinline__ ushort f2bf(float f) {
    unsigned u = __builtin_bit_cast(unsigned, f);
    unsigned r = u + 0x7fffu + ((u >> 16) & 1u);
    return (ushort)(r >> 16);
}

__device__ __forceinline__ void gld16(const void* g, void* l) {
    __builtin_amdgcn_global_load_lds((__attribute__((address_space(1))) void*)g,
                                     (__attribute__((address_space(3))) void*)l, 16, 0, 0);
}

// ---------------- cast kernels ----------------
__global__ void cast4_k(const float4* __restrict__ in, ushort* __restrict__ out, long n4) {
    long i = (long)blockIdx.x * blockDim.x + threadIdx.x;
    if (i >= n4) return;
    float4 v = in[i];
    ushort4 o = { f2bf(v.x), f2bf(v.y), f2bf(v.z), f2bf(v.w) };
    *(ushort4*)(out + i * 4) = o;
}

__global__ void cast_win_k(const float4* __restrict__ in, ushort* __restrict__ out) {
    long i = (long)blockIdx.x * blockDim.x + threadIdx.x;  // n4 = 8576*2048/4
    if (i >= (long)8576 * 2048 / 4) return;
    ushort4 o;
    if (i < (long)8480 * 2048 / 4) {
        float4 v = in[i];
        o = { f2bf(v.x), f2bf(v.y), f2bf(v.z), f2bf(v.w) };
    } else {
        o = { 0, 0, 0, 0 };
    }
    *(ushort4*)(out + i * 4) = o;
}

// ---------------- bf16 MFMA GEMM: C[M,N] = A[M,K] * B[N,K]^T ----------------
template <int OUTBF>
__global__ __launch_bounds__(256) void gemm_bt_k(const ushort* __restrict__ A,
                                                 const ushort* __restrict__ Bm,
                                                 void* __restrict__ Cout,
                                                 int M, int Ncols, int Kd) {
    __shared__ ushort As[128 * 32];
    __shared__ ushort Bs[128 * 32];
    const int tid = threadIdx.x;
    const int lane = tid & 63, wave = tid >> 6;
    const int wm = wave >> 1, wn = wave & 1;
    const long m0 = (long)blockIdx.y * 128, n0 = (long)blockIdx.x * 128;

    f32x4 zero = { 0.f, 0.f, 0.f, 0.f };
    f32x4 acc[4][4];
#pragma unroll
    for (int i = 0; i < 4; i++)
#pragma unroll
        for (int j = 0; j < 4; j++) acc[i][j] = zero;

    const int eb = wave * 512 + lane * 8;
    for (int kt = 0; kt < Kd; kt += 32) {
        __syncthreads();
#pragma unroll
        for (int j = 0; j < 2; j++) {
            int e = j * 2048 + eb;
            int row = e >> 5, col = e & 31;
            gld16(A + (m0 + row) * Kd + kt + col, As + e);
            gld16(Bm + (n0 + row) * Kd + kt + col, Bs + e);
        }
        asm volatile("s_waitcnt vmcnt(0)" ::: "memory");
        __syncthreads();
        s16x8 af[4], bfr[4];
        const int ra = (wm * 64 + (lane & 15)) * 32 + (lane >> 4) * 8;
        const int rb = (wn * 64 + (lane & 15)) * 32 + (lane >> 4) * 8;
#pragma unroll
        for (int i = 0; i < 4; i++) {
            af[i] = *(const s16x8*)(As + ra + i * 512);
            bfr[i] = *(const s16x8*)(Bs + rb + i * 512);
        }
#pragma unroll
        for (int mi = 0; mi < 4; mi++)
#pragma unroll
            for (int ni = 0; ni < 4; ni++)
                acc[mi][ni] = __builtin_amdgcn_mfma_f32_16x16x32_bf16(af[mi], bfr[ni], acc[mi][ni], 0, 0, 0);
    }
    const long crow = m0 + wm * 64 + ((lane >> 4) << 2);
    const long ccol = n0 + wn * 64 + (lane & 15);
#pragma unroll
    for (int mi = 0; mi < 4; mi++)
#pragma unroll
        for (int ni = 0; ni < 4; ni++)
#pragma unroll
            for (int r = 0; r < 4; r++) {
                long idx = (crow + mi * 16 + r) * (long)Ncols + ccol + ni * 16;
                if (OUTBF) ((ushort*)Cout)[idx] = f2bf(acc[mi][ni][r]);
                else       ((float*)Cout)[idx] = acc[mi][ni][r];
            }
}

// ---------------- causal conv (K=4) + SiLU ----------------
__global__ void conv_silu_k(const ushort* __restrict__ zx, const float* __restrict__ w,
                            const float* __restrict__ bias, ushort* __restrict__ out) {
    const int bx = blockIdx.x;            // grid 4096*17
    const int t = bx / 17, cg = bx % 17;
    const int c = cg * 256 + threadIdx.x; // < 4352
    const int bi = t >> 11, pos = t & 2047;
    float acc = bias[c];
#pragma unroll
    for (int k = 0; k < 4; k++) {
        int p = pos + k - 3;
        if (p >= 0) acc += bf2f(zx[((long)(bi * 2048 + p)) * 8576 + 4096 + c]) * w[c * 4 + k];
    }
    out[(long)t * 4352 + c] = f2bf(acc / (1.f + __expf(-acc)));
}

// ---------------- dt softplus/clip + per-chunk cumsum ----------------
__global__ void prep_k(const ushort* __restrict__ zx, const float* __restrict__ dt_bias,
                       const float* __restrict__ A_log, float* __restrict__ dtp,
                       float* __restrict__ dacs) {
    const int bx = blockIdx.x;  // 512 = bi(2) x cc(8) x h(32)
    const int h = bx & 31, cc = (bx >> 5) & 7, bi = bx >> 8;
    const int lane = threadIdx.x;  // 64
    const float A = -__expf(A_log[h]);
    const float bsh = dt_bias[h];
    float v[4], cs[4];
    float run = 0.f;
#pragma unroll
    for (int j = 0; j < 4; j++) {
        int pos = cc * 256 + lane * 4 + j;
        float raw = bf2f(zx[((long)(bi * 2048 + pos)) * 8576 + 8448 + h]) + bsh;
        float sp = (raw > 20.f) ? raw : log1pf(__expf(raw));
        float d = fminf(fmaxf(sp, 0.001f), 0.1f);
        v[j] = d;
        run += d * A;
        cs[j] = run;
    }
    float tot = run, pre = run;
    for (int off = 1; off < 64; off <<= 1) {
        float u = __shfl_up(pre, off, 64);
        if (lane >= off) pre += u;
    }
    float excl = pre - tot;
    const long base = ((long)(bi * 32 + h)) * 2048 + cc * 256 + lane * 4;
#pragma unroll
    for (int j = 0; j < 4; j++) { dtp[base + j] = v[j]; dacs[base + j] = excl + cs[j]; }
}

// ---------------- CB[l,s] = C[l,:].B[s,:] per chunk ----------------
__global__ __launch_bounds__(256) void cb_k(const ushort* __restrict__ xbcc, float* __restrict__ CB) {
    const int bx = blockIdx.x;  // 128 = bc(16) x lt(8)
    const int lt = bx & 7, bc = bx >> 3;
    const int bi = bc >> 3, cc = bc & 7;
    __shared__ ushort Bs[256][136];
    __shared__ ushort Cs2[32][136];
    const int tid = threadIdx.x;
    const long tbase = (long)bi * 2048 + cc * 256;
#pragma unroll
    for (int r = 0; r < 16; r++) {
        int u = tid + r * 256; int s = u >> 4, seg = u & 15;
        *(s16x8*)&Bs[s][seg * 8] = *(const s16x8*)&xbcc[(tbase + s) * 4352 + 4096 + seg * 8];
    }
#pragma unroll
    for (int r = 0; r < 2; r++) {
        int u = tid + r * 256; int s = u >> 4, seg = u & 15;
        *(s16x8*)&Cs2[s][seg * 8] = *(const s16x8*)&xbcc[(tbase + lt * 32 + s) * 4352 + 4224 + seg * 8];
    }
    __syncthreads();
    const int l = tid >> 3, sg = tid & 7;
    float acc[32];
#pragma unroll
    for (int j = 0; j < 32; j++) acc[j] = 0.f;
    for (int n = 0; n < 128; n++) {
        float cv = bf2f(Cs2[l][n]);
#pragma unroll
        for (int j = 0; j < 32; j++) acc[j] += cv * bf2f(Bs[sg + j * 8][n]);
    }
    const long obase = ((long)bc) * 65536 + (long)(lt * 32 + l) * 256 + sg;
#pragma unroll
    for (int j = 0; j < 32; j++) CB[obase + j * 8] = acc[j];
}

// ---------------- intra-chunk masked einsum via MFMA ----------------
// grid: 1024 = bi(2) x cc(8) x h(32) x ltile(2); 256 thr (4 waves, wm x wn 2x2)
// Y[l,p] = sum_{s<=l} M[l,s] X[s,p],  M = CB * exp(dA_l - dA_s) * dt_s
//   factored per 32-s-block sb with anchor R = dA[sb*32+31]:
//   M = CB * E * F,  E = exp(dA_l - R) (per A-frag),  F_s = exp(R - dA_s)*dt_s
// A-frag built in registers (CB from global); B-frag from LDS Xt[p][s]
// ([col][k] layout, same as gemm_bt_k's Bs) via ds_read_b128.
// Xt row stride 40 elems (80B, 16B-aligned); s-column XOR-swizzled by
// ((p>>3)&3)<<3 to cut write conflicts to ~4-way while reads stay b128.
__global__ __launch_bounds__(256) void intra_mfma_k(const ushort* __restrict__ xbcc,
                                                    const float* __restrict__ CB,
                                                    const float* __restrict__ dtp,
                                                    const float* __restrict__ dacs,
                                                    float* __restrict__ yf) {
    const int bx = blockIdx.x;
    const int ltile = bx & 1, h = (bx >> 1) & 31, cc = (bx >> 6) & 7, bi = bx >> 9;
    const int tid = threadIdx.x, lane = tid & 63, wave = tid >> 6;
    const int wm = wave >> 1, wn = wave & 1;

    __shared__ float dA_s[256];
    __shared__ float F_s[256];
    __shared__ ushort Xt[128][40];  // [p][s^swz], 20 KB

    const long dbase = ((long)(bi * 32 + h)) * 2048 + cc * 256;
    {
        float a = dacs[dbase + tid];
        float r = dacs[dbase + (tid | 31)];
        dA_s[tid] = a;
        F_s[tid] = __expf(r - a) * dtp[dbase + tid];
    }
    __syncthreads();

    int lch[4];
    float dAl[4];
#pragma unroll
    for (int mi = 0; mi < 4; mi++) {
        lch[mi] = ltile * 128 + wm * 64 + mi * 16 + (lane & 15);
        dAl[mi] = dA_s[lch[mi]];
    }

    f32x4 zero = { 0.f, 0.f, 0.f, 0.f };
    f32x4 acc[4][4];
#pragma unroll
    for (int i = 0; i < 4; i++)
#pragma unroll
        for (int j = 0; j < 4; j++) acc[i][j] = zero;

    const long tbase = (long)bi * 2048 + cc * 256;
    const long cbbase = ((long)(bi * 8 + cc)) * 65536;
    const int nsb = ltile * 4 + 4;

    for (int sb = 0; sb < nsb; ++sb) {
        __syncthreads();
        // stage X^T for this s-block: X[sb*32+s][h*128+p] -> Xt[p][s^swz]
#pragma unroll
        for (int i = 0; i < 2; i++) {
            int c = tid + i * 256;          // 0..511
            int s = c >> 4;                 // 0..31
            int p0 = (c & 15) * 8;          // 0..120
            s16x8 v = *(const s16x8*)&xbcc[(tbase + sb * 32 + s) * 4352 + h * 128 + p0];
            int scol = s ^ (((p0 >> 3) & 3) << 3);
#pragma unroll
            for (int j = 0; j < 8; j++) Xt[p0 + j][scol] = (ushort)v[j];
        }
        __syncthreads();

        s16x8 bf[4];
#pragma unroll
        for (int ni = 0; ni < 4; ni++) {
            int p = wn * 64 + ni * 16 + (lane & 15);
            int scol = (((lane >> 4) ^ ((p >> 3) & 3))) * 8;
            bf[ni] = *(const s16x8*)&Xt[p][scol];
        }

        const float Rsb = dA_s[sb * 32 + 31];
        const int s0 = sb * 32 + (lane >> 4) * 8;
#pragma unroll
        for (int mi = 0; mi < 4; mi++) {
            const int lb = lch[mi] >> 5;
            if (sb > lb) continue;
            const float* cbrow = CB + cbbase + (long)lch[mi] * 256 + s0;
            float4 c0 = *(const float4*)cbrow;
            float4 c1 = *(const float4*)(cbrow + 4);
            float E = __expf(dAl[mi] - Rsb);
            float m[8];
            m[0] = c0.x * E * F_s[s0 + 0]; m[1] = c0.y * E * F_s[s0 + 1];
            m[2] = c0.z * E * F_s[s0 + 2]; m[3] = c0.w * E * F_s[s0 + 3];
            m[4] = c1.x * E * F_s[s0 + 4]; m[5] = c1.y * E * F_s[s0 + 5];
            m[6] = c1.z * E * F_s[s0 + 6]; m[7] = c1.w * E * F_s[s0 + 7];
            if (sb == lb) {
#pragma unroll
                for (int j = 0; j < 8; j++)
                    if (s0 + j > lch[mi]) m[j] = 0.f;
            }
            s16x8 a;
#pragma unroll
            for (int j = 0; j < 8; j++) a[j] = (short)f2bf(m[j]);
#pragma unroll
            for (int ni = 0; ni < 4; ni++)
                acc[mi][ni] = __builtin_amdgcn_mfma_f32_16x16x32_bf16(a, bf[ni], acc[mi][ni], 0, 0, 0);
        }
    }

    const long crow = tbase + ltile * 128 + wm * 64 + ((lane >> 4) << 2);
    const int ccol = h * 128 + wn * 64 + (lane & 15);
#pragma unroll
    for (int mi = 0; mi < 4; mi++)
#pragma unroll
        for (int ni = 0; ni < 4; ni++)
#pragma unroll
            for (int r = 0; r < 4; r++)
                yf[(crow + mi * 16 + r) * 4096 + ccol + ni * 16] = acc[mi][ni][r];
}

// ---------------- per-chunk end states ----------------
__global__ __launch_bounds__(256) void states_k(const ushort* __restrict__ xbcc, const float* __restrict__ dtp,
                                                const float* __restrict__ dacs, float* __restrict__ states) {
    const int bx = blockIdx.x;  // 2048 = bi(2) x cc(8) x h(32) x pb(4)
    const int pb = bx & 3, h = (bx >> 2) & 31, cc = (bx >> 7) & 7, bi = bx >> 10;
    __shared__ ushort Bsh[128][128];
    __shared__ ushort xsh[128][32];
    __shared__ float wl[256];
    const int tid = threadIdx.x;
    const long tbase = (long)bi * 2048 + cc * 256;
    const long dbase = ((long)(bi * 32 + h)) * 2048 + cc * 256;
    {
        float last = dacs[dbase + 255];
        wl[tid] = __expf(last - dacs[dbase + tid]) * dtp[dbase + tid];
    }
    const int pt = tid & 31, ng = tid >> 5;
    float acc[16];
#pragma unroll
    for (int j = 0; j < 16; j++) acc[j] = 0.f;
    for (int ph = 0; ph < 2; ph++) {
        __syncthreads();
#pragma unroll
        for (int r = 0; r < 8; r++) {
            int u = tid + r * 256; int s = u >> 4, seg = u & 15;
            *(s16x8*)&Bsh[s][seg * 8] = *(const s16x8*)&xbcc[(tbase + ph * 128 + s) * 4352 + 4096 + seg * 8];
        }
#pragma unroll
        for (int r = 0; r < 2; r++) {
            int u = tid + r * 256; int s = u >> 2, seg = u & 3;
            *(s16x8*)&xsh[s][seg * 8] = *(const s16x8*)&xbcc[(tbase + ph * 128 + s) * 4352 + h * 128 + pb * 32 + seg * 8];
        }
        __syncthreads();
        for (int l = 0; l < 128; l++) {
            float xv = wl[ph * 128 + l] * bf2f(xsh[l][pt]);
            const unsigned* br = (const unsigned*)&Bsh[l][ng * 16];
#pragma unroll
            for (int jj = 0; jj < 8; jj++) {
                unsigned v = br[jj];
                acc[jj * 2]     += xv * bf2f((ushort)(v & 0xffffu));
                acc[jj * 2 + 1] += xv * bf2f((ushort)(v >> 16));
            }
        }
    }
    float* out = &states[((((long)(bi * 8 + cc)) * 32 + h) * 128 + pb * 32 + pt) * 128 + ng * 16];
#pragma unroll
    for (int j = 0; j < 16; j++) out[j] = acc[j];
}

// ---------------- chunk recurrence: states -> prev_states (in place) ----------------
__global__ void rec_k(float* __restrict__ states, const float* __restrict__ dacs) {
    const int i = blockIdx.x * 256 + threadIdx.x;  // 1,048,576
    const int n = i & 127, p = (i >> 7) & 127, h = (i >> 14) & 31, bi = i >> 19;
    const long dbase = ((long)(bi * 32 + h)) * 2048;
    float run = 0.f;
    for (int cc = 0; cc < 8; cc++) {
        const long off = ((((long)(bi * 8 + cc)) * 32 + h) * 128 + p) * 128 + n;
        float st = states[off];
        states[off] = run;
        float dec = dacs[dbase + cc * 256 + 255];
        run = run * __expf(dec) + st;
    }
}

// ---------------- inter-chunk contribution ----------------
__global__ __launch_bounds__(256) void inter_k(const ushort* __restrict__ xbcc, const float* __restrict__ states,
                                               const float* __restrict__ dacs, float* __restrict__ y) {
    const int bx = blockIdx.x;  // 4096 = bi(2) x cc(8) x h(32) x lb(8)
    const int lb = bx & 7, h = (bx >> 3) & 31, cc = (bx >> 8) & 7, bi = bx >> 11;
    __shared__ float Cs[32][129];
    __shared__ ushort pT[128][132];  // prev transposed [n][p] bf16
    const int tid = threadIdx.x;
    const long tbase = (long)bi * 2048 + cc * 256;
#pragma unroll
    for (int r = 0; r < 16; r++) {
        int u = tid + r * 256; int ll = u >> 7, n = u & 127;
        Cs[ll][n] = bf2f(xbcc[(tbase + lb * 32 + ll) * 4352 + 4224 + n]);
    }
    const long sbase = ((((long)(bi * 8 + cc)) * 32 + h) * 128) * 128;
    for (int r = 0; r < 64; r++) {
        int u = r * 256 + tid; int p = u >> 7, n = u & 127;
        pT[n][p] = f2bf(states[sbase + u]);
    }
    __syncthreads();
    const int l_loc = tid >> 3, pg = tid & 7;
    float acc[16];
#pragma unroll
    for (int j = 0; j < 16; j++) acc[j] = 0.f;
    for (int n = 0; n < 128; n++) {
        float cv = Cs[l_loc][n];
        const unsigned* pr = (const unsigned*)&pT[n][pg * 16];
#pragma unroll
        for (int jj = 0; jj < 8; jj++) {
            unsigned v = pr[jj];
            acc[jj * 2]     += cv * bf2f((ushort)(v & 0xffffu));
            acc[jj * 2 + 1] += cv * bf2f((ushort)(v >> 16));
        }
    }
    const int l = lb * 32 + l_loc;
    const long tok = tbase + l;
    const float el = __expf(dacs[((long)(bi * 32 + h)) * 2048 + cc * 256 + l]);
    float* yr = &y[tok * 4096 + h * 128 + pg * 16];
#pragma unroll
    for (int j = 0; j < 16; j++) yr[j] += el * acc[j];
}

// ---------------- gate (silu(z)) + D*x + RMSNorm -> bf16 ----------------
__global__ __launch_bounds__(256) void gate_rms_k(const float* __restrict__ y, const ushort* __restrict__ zx,
                                                  const ushort* __restrict__ xbcc, const float* __restrict__ Dv,
                                                  const float* __restrict__ norm_w, ushort* __restrict__ yb) {
    const int t = blockIdx.x, tid = threadIdx.x;
    const float* yr = &y[(long)t * 4096];
    const ushort* zr = &zx[(long)t * 8576];
    const ushort* xr = &xbcc[(long)t * 4352];
    float g[16];
    float ss = 0.f;
#pragma unroll
    for (int j = 0; j < 16; j++) {
        int i = j * 256 + tid;
        float z = bf2f(zr[i]);
        float yv = yr[i] + Dv[i >> 7] * bf2f(xr[i]);
        float gv = yv * (z / (1.f + __expf(-z)));
        g[j] = gv;
        ss += gv * gv;
    }
#pragma unroll
    for (int off = 32; off > 0; off >>= 1) ss += __shfl_xor(ss, off, 64);
    __shared__ float red[4];
    if ((tid & 63) == 0) red[tid >> 6] = ss;
    __syncthreads();
    float tot = red[0] + red[1] + red[2] + red[3];
    float sc = rsqrtf(tot * (1.f / 4096.f) + 1e-6f);
#pragma unroll
    for (int j = 0; j < 16; j++) {
        int i = j * 256 + tid;
        yb[(long)t * 4096 + i] = f2bf(g[j] * sc * norm_w[i]);
    }
}

// ---------------------------------------------------------------------------
extern "C" void kernel_launch(void* const* d_in, const int* in_sizes, int n_in,
                              void* d_out, int out_size, void* d_ws, size_t ws_size,
                              hipStream_t stream) {
    const float* x       = (const float*)d_in[0];
    const float* W_in    = (const float*)d_in[1];
    const float* conv_w  = (const float*)d_in[2];
    const float* conv_b  = (const float*)d_in[3];
    const float* dt_bias = (const float*)d_in[4];
    const float* A_log   = (const float*)d_in[5];
    const float* Dv      = (const float*)d_in[6];
    const float* norm_w  = (const float*)d_in[7];
    const float* W_out   = (const float*)d_in[8];

    char* w8 = (char*)d_ws;
    ushort* xb    = (ushort*)(w8 + 0L);
    ushort* yb    = (ushort*)(w8 + 0L);           // alias (xb dead after GEMM1)
    ushort* winb  = (ushort*)(w8 + 16777216L);
    ushort* woutb = (ushort*)(w8 + 33554432L);    // alias (winb dead after GEMM1)
    ushort* zx    = (ushort*)(w8 + 51904512L);
    ushort* xbcc  = (ushort*)(w8 + 122159104L);
    float*  dtp   = (float*)(w8 + 157810688L);
    float*  dacs  = (float*)(w8 + 158334976L);
    float*  cb    = (float*)(w8 + 158859264L);
    float*  yf    = (float*)(w8 + 163053568L);
    float*  st    = (float*)(w8 + 230162432L);

    cast4_k<<<8192, 256, 0, stream>>>((const float4*)x, xb, 2097152L);
    cast_win_k<<<17152, 256, 0, stream>>>((const float4*)W_in, winb);
    gemm_bt_k<1><<<dim3(67, 32), 256, 0, stream>>>(xb, winb, (void*)zx, 4096, 8576, 2048);
    cast4_k<<<8192, 256, 0, stream>>>((const float4*)W_out, woutb, 2097152L);
    conv_silu_k<<<69632, 256, 0, stream>>>(zx, conv_w, conv_b, xbcc);
    prep_k<<<512, 64, 0, stream>>>(zx, dt_bias, A_log, dtp, dacs);
    cb_k<<<128, 256, 0, stream>>>(xbcc, cb);
    intra_mfma_k<<<1024, 256, 0, stream>>>(xbcc, cb, dtp, dacs, yf);
    states_k<<<2048, 256, 0, stream>>>(xbcc, dtp, dacs, st);
    rec_k<<<4096, 256, 0, stream>>>(st, dacs);
    inter_k<<<4096, 256, 0, stream>>>(xbcc, st, dacs, yf);
    gate_rms_k<<<4096, 256, 0, stream>>>(yf, zx, xbcc, Dv, norm_w, yb);
    gemm_bt_k<0><<<dim3(16, 32), 256, 0, stream>>>(yb, woutb, d_out, 4096, 2048, 4096);
}

// Round 4
// 613.150 us; speedup vs baseline: 1.6556x; 1.2932x over previous
//
#include <hip/hip_runtime.h>

// ---------------------------------------------------------------------------
// SSM (Mamba2-style) fused forward for MI355X.
// R3: (1) GEMM grid XCD-swizzled supertiling (bid&7 -> XCD owns 4-M-tile band)
//     (2) global transpose xT[bc][h][p][s] + Bt[bc][n][s] -> all scan MFMA
//         operands k-contiguous in global; intra/states/inter are LDS-free
//         MFMA kernels with direct-global fragments.
// ws layout (bytes):
//   xb     @0          (dead after GEMM1)  | xT @0 33,554,432 (after conv)
//   yb     @0          33,554,432 (gate output, after xT dead)
//   winb   @16,777,216 35,127,296 (dead after GEMM1)
//   woutb  @33,554,432 16,777,216
//   Bt     @50,331,648 1,048,576
//   zx     @51,904,512 70,254,592
//   xbcc   @122,159,104 35,651,584
//   dtp    @157,810,688 524,288
//   dacs   @158,334,976 524,288
//   cb     @158,859,264 4,194,304
//   yf     @163,053,568 67,108,864
//   st     @230,162,432 33,554,432
//   TOTAL 263,716,864
// ---------------------------------------------------------------------------

typedef short s16x8 __attribute__((ext_vector_type(8)));
typedef float f32x4 __attribute__((ext_vector_type(4)));

__device__ __forceinline__ float bf2f(ushort u) {
    return __builtin_bit_cast(float, (unsigned)u << 16);
}
__device__ __forceinline__ ushort f2bf(float f) {
    unsigned u = __builtin_bit_cast(unsigned, f);
    unsigned r = u + 0x7fffu + ((u >> 16) & 1u);
    return (ushort)(r >> 16);
}

__device__ __forceinline__ void gld16(const void* g, void* l) {
    __builtin_amdgcn_global_load_lds((__attribute__((address_space(1))) void*)g,
                                     (__attribute__((address_space(3))) void*)l, 16, 0, 0);
}

// ---------------- cast kernels ----------------
__global__ void cast4_k(const float4* __restrict__ in, ushort* __restrict__ out, long n4) {
    long i = (long)blockIdx.x * blockDim.x + threadIdx.x;
    if (i >= n4) return;
    float4 v = in[i];
    ushort4 o = { f2bf(v.x), f2bf(v.y), f2bf(v.z), f2bf(v.w) };
    *(ushort4*)(out + i * 4) = o;
}

__global__ void cast_win_k(const float4* __restrict__ in, ushort* __restrict__ out) {
    long i = (long)blockIdx.x * blockDim.x + threadIdx.x;  // n4 = 8576*2048/4
    if (i >= (long)8576 * 2048 / 4) return;
    ushort4 o;
    if (i < (long)8480 * 2048 / 4) {
        float4 v = in[i];
        o = { f2bf(v.x), f2bf(v.y), f2bf(v.z), f2bf(v.w) };
    } else {
        o = { 0, 0, 0, 0 };
    }
    *(ushort4*)(out + i * 4) = o;
}

// ---------------- bf16 MFMA GEMM: C[M,N] = A[M,K] * B[N,K]^T ----------------
// 1-D grid = 32 * NT blocks. XCD-swizzle: xcd=bid&7 owns M-tiles [4*xcd,4*xcd+4),
// n-major within the band so 4 consecutive blocks share one B-panel and the
// 2 MB A-band stays L2-resident per XCD.
template <int OUTBF>
__global__ __launch_bounds__(256) void gemm_bt_k(const ushort* __restrict__ A,
                                                 const ushort* __restrict__ Bm,
                                                 void* __restrict__ Cout,
                                                 int Ncols, int Kd) {
    __shared__ ushort As[128 * 32];
    __shared__ ushort Bs[128 * 32];
    const int bid = blockIdx.x;
    const int xcd = bid & 7, w = bid >> 3;
    const int mt = xcd * 4 + (w & 3), nt = w >> 2;
    const int tid = threadIdx.x;
    const int lane = tid & 63, wave = tid >> 6;
    const int wm = wave >> 1, wn = wave & 1;
    const long m0 = (long)mt * 128, n0 = (long)nt * 128;

    f32x4 zero = { 0.f, 0.f, 0.f, 0.f };
    f32x4 acc[4][4];
#pragma unroll
    for (int i = 0; i < 4; i++)
#pragma unroll
        for (int j = 0; j < 4; j++) acc[i][j] = zero;

    const int eb = wave * 512 + lane * 8;
    for (int kt = 0; kt < Kd; kt += 32) {
        __syncthreads();
#pragma unroll
        for (int j = 0; j < 2; j++) {
            int e = j * 2048 + eb;
            int row = e >> 5, col = e & 31;
            gld16(A + (m0 + row) * Kd + kt + col, As + e);
            gld16(Bm + (n0 + row) * Kd + kt + col, Bs + e);
        }
        asm volatile("s_waitcnt vmcnt(0)" ::: "memory");
        __syncthreads();
        s16x8 af[4], bfr[4];
        const int ra = (wm * 64 + (lane & 15)) * 32 + (lane >> 4) * 8;
        const int rb = (wn * 64 + (lane & 15)) * 32 + (lane >> 4) * 8;
#pragma unroll
        for (int i = 0; i < 4; i++) {
            af[i] = *(const s16x8*)(As + ra + i * 512);
            bfr[i] = *(const s16x8*)(Bs + rb + i * 512);
        }
#pragma unroll
        for (int mi = 0; mi < 4; mi++)
#pragma unroll
            for (int ni = 0; ni < 4; ni++)
                acc[mi][ni] = __builtin_amdgcn_mfma_f32_16x16x32_bf16(af[mi], bfr[ni], acc[mi][ni], 0, 0, 0);
    }
    const long crow = m0 + wm * 64 + ((lane >> 4) << 2);
    const long ccol = n0 + wn * 64 + (lane & 15);
#pragma unroll
    for (int mi = 0; mi < 4; mi++)
#pragma unroll
        for (int ni = 0; ni < 4; ni++)
#pragma unroll
            for (int r = 0; r < 4; r++) {
                long idx = (crow + mi * 16 + r) * (long)Ncols + ccol + ni * 16;
                if (OUTBF) ((ushort*)Cout)[idx] = f2bf(acc[mi][ni][r]);
                else       ((float*)Cout)[idx] = acc[mi][ni][r];
            }
}

// ---------------- causal conv (K=4) + SiLU ----------------
__global__ void conv_silu_k(const ushort* __restrict__ zx, const float* __restrict__ w,
                            const float* __restrict__ bias, ushort* __restrict__ out) {
    const int bx = blockIdx.x;            // grid 4096*17
    const int t = bx / 17, cg = bx % 17;
    const int c = cg * 256 + threadIdx.x; // < 4352
    const int bi = t >> 11, pos = t & 2047;
    float acc = bias[c];
#pragma unroll
    for (int k = 0; k < 4; k++) {
        int p = pos + k - 3;
        if (p >= 0) acc += bf2f(zx[((long)(bi * 2048 + p)) * 8576 + 4096 + c]) * w[c * 4 + k];
    }
    out[(long)t * 4352 + c] = f2bf(acc / (1.f + __expf(-acc)));
}

// ---------------- dt softplus/clip + per-chunk cumsum ----------------
__global__ void prep_k(const ushort* __restrict__ zx, const float* __restrict__ dt_bias,
                       const float* __restrict__ A_log, float* __restrict__ dtp,
                       float* __restrict__ dacs) {
    const int bx = blockIdx.x;  // 512 = bi(2) x cc(8) x h(32)
    const int h = bx & 31, cc = (bx >> 5) & 7, bi = bx >> 8;
    const int lane = threadIdx.x;  // 64
    const float A = -__expf(A_log[h]);
    const float bsh = dt_bias[h];
    float v[4], cs[4];
    float run = 0.f;
#pragma unroll
    for (int j = 0; j < 4; j++) {
        int pos = cc * 256 + lane * 4 + j;
        float raw = bf2f(zx[((long)(bi * 2048 + pos)) * 8576 + 8448 + h]) + bsh;
        float sp = (raw > 20.f) ? raw : log1pf(__expf(raw));
        float d = fminf(fmaxf(sp, 0.001f), 0.1f);
        v[j] = d;
        run += d * A;
        cs[j] = run;
    }
    float tot = run, pre = run;
    for (int off = 1; off < 64; off <<= 1) {
        float u = __shfl_up(pre, off, 64);
        if (lane >= off) pre += u;
    }
    float excl = pre - tot;
    const long base = ((long)(bi * 32 + h)) * 2048 + cc * 256 + lane * 4;
#pragma unroll
    for (int j = 0; j < 4; j++) { dtp[base + j] = v[j]; dacs[base + j] = excl + cs[j]; }
}

// ---------------- transpose: xbcc[s][slot*128+p] -> xT/Bt [.][p][s] ----------------
// grid dim3(8 stile, 33 slot, 16 bc); slot<32 -> xT head slot, slot==32 -> Bt.
__global__ __launch_bounds__(256) void xpose_k(const ushort* __restrict__ xbcc,
                                               ushort* __restrict__ xT,
                                               ushort* __restrict__ Bt) {
    __shared__ ushort T[32][136];
    const int stile = blockIdx.x, slot = blockIdx.y, bc = blockIdx.z;
    const int tid = threadIdx.x;
    const long tbase = (long)bc * 256 + stile * 32;
#pragma unroll
    for (int i = 0; i < 2; i++) {
        int u = tid + i * 256;            // 512 = 32 s x 16 seg
        int s = u >> 4, p0 = (u & 15) * 8;
        s16x8 v = *(const s16x8*)&xbcc[(tbase + s) * 4352 + slot * 128 + p0];
#pragma unroll
        for (int j = 0; j < 8; j++) T[s][p0 + j] = (ushort)v[j];
    }
    __syncthreads();
    ushort* dst = (slot < 32) ? (xT + ((long)(bc * 32 + slot) * 128) * 256)
                              : (Bt + ((long)bc * 128) * 256);
#pragma unroll
    for (int i = 0; i < 2; i++) {
        int u = tid + i * 256;            // 512 = 128 p x 4 sg
        int p = u >> 2, s0 = (u & 3) * 8;
        s16x8 o;
#pragma unroll
        for (int j = 0; j < 8; j++) o[j] = (short)T[s0 + j][p];
        *(s16x8*)&dst[(long)p * 256 + stile * 32 + s0] = o;
    }
}

// ---------------- CB[l,s] = C[l,:].B[s,:] per chunk ----------------
__global__ __launch_bounds__(256) void cb_k(const ushort* __restrict__ xbcc, float* __restrict__ CB) {
    const int bx = blockIdx.x;  // 128 = bc(16) x lt(8)
    const int lt = bx & 7, bc = bx >> 3;
    const int bi = bc >> 3, cc = bc & 7;
    __shared__ ushort Bs[256][136];
    __shared__ ushort Cs2[32][136];
    const int tid = threadIdx.x;
    const long tbase = (long)bi * 2048 + cc * 256;
#pragma unroll
    for (int r = 0; r < 16; r++) {
        int u = tid + r * 256; int s = u >> 4, seg = u & 15;
        *(s16x8*)&Bs[s][seg * 8] = *(const s16x8*)&xbcc[(tbase + s) * 4352 + 4096 + seg * 8];
    }
#pragma unroll
    for (int r = 0; r < 2; r++) {
        int u = tid + r * 256; int s = u >> 4, seg = u & 15;
        *(s16x8*)&Cs2[s][seg * 8] = *(const s16x8*)&xbcc[(tbase + lt * 32 + s) * 4352 + 4224 + seg * 8];
    }
    __syncthreads();
    const int l = tid >> 3, sg = tid & 7;
    float acc[32];
#pragma unroll
    for (int j = 0; j < 32; j++) acc[j] = 0.f;
    for (int n = 0; n < 128; n++) {
        float cv = bf2f(Cs2[l][n]);
#pragma unroll
        for (int j = 0; j < 32; j++) acc[j] += cv * bf2f(Bs[sg + j * 8][n]);
    }
    const long obase = ((long)bc) * 65536 + (long)(lt * 32 + l) * 256 + sg;
#pragma unroll
    for (int j = 0; j < 32; j++) CB[obase + j * 8] = acc[j];
}

// ---------------- intra-chunk masked einsum via MFMA (LDS-free B) ----------------
// grid: 1024 = bi(2) x cc(8) x h(32) x ltile(2); 256 thr (4 waves 2x2)
// Y[l,p] = sum_{s<=l} M[l,s] X[s,p],  M = CB * E * F (per-32-block anchored)
// A built in registers from CB(global f32); B-frag direct from xT (k=s contig).
__global__ __launch_bounds__(256) void intra_mfma_k(const ushort* __restrict__ xT,
                                                    const float* __restrict__ CB,
                                                    const float* __restrict__ dtp,
                                                    const float* __restrict__ dacs,
                                                    float* __restrict__ yf) {
    const int bx = blockIdx.x;
    const int ltile = bx & 1, h = (bx >> 1) & 31, cc = (bx >> 6) & 7, bi = bx >> 9;
    const int tid = threadIdx.x, lane = tid & 63, wave = tid >> 6;
    const int wm = wave >> 1, wn = wave & 1;

    __shared__ float dA_s[256];
    __shared__ float F_s[256];

    const long dbase = ((long)(bi * 32 + h)) * 2048 + cc * 256;
    {
        float a = dacs[dbase + tid];
        float r = dacs[dbase + (tid | 31)];
        dA_s[tid] = a;
        F_s[tid] = __expf(r - a) * dtp[dbase + tid];
    }
    __syncthreads();

    int lch[4];
    float dAl[4];
#pragma unroll
    for (int mi = 0; mi < 4; mi++) {
        lch[mi] = ltile * 128 + wm * 64 + mi * 16 + (lane & 15);
        dAl[mi] = dA_s[lch[mi]];
    }

    f32x4 zero = { 0.f, 0.f, 0.f, 0.f };
    f32x4 acc[4][4];
#pragma unroll
    for (int i = 0; i < 4; i++)
#pragma unroll
        for (int j = 0; j < 4; j++) acc[i][j] = zero;

    const long tbase = (long)bi * 2048 + cc * 256;
    const long cbbase = ((long)(bi * 8 + cc)) * 65536;
    const ushort* xrow = xT + (((long)(bi * 8 + cc) * 32 + h) * 128) * 256;
    const int nsb = ltile * 4 + 4;

    for (int sb = 0; sb < nsb; ++sb) {
        const int soff = sb * 32 + (lane >> 4) * 8;
        s16x8 bf[4];
#pragma unroll
        for (int ni = 0; ni < 4; ni++) {
            int p = wn * 64 + ni * 16 + (lane & 15);
            bf[ni] = *(const s16x8*)&xrow[(long)p * 256 + soff];
        }
        const float Rsb = dA_s[sb * 32 + 31];
        const int s0 = soff;
#pragma unroll
        for (int mi = 0; mi < 4; mi++) {
            const int lb = lch[mi] >> 5;
            if (sb > lb) continue;
            const float* cbrow = CB + cbbase + (long)lch[mi] * 256 + s0;
            float4 c0 = *(const float4*)cbrow;
            float4 c1 = *(const float4*)(cbrow + 4);
            float E = __expf(dAl[mi] - Rsb);
            float m[8];
            m[0] = c0.x * E * F_s[s0 + 0]; m[1] = c0.y * E * F_s[s0 + 1];
            m[2] = c0.z * E * F_s[s0 + 2]; m[3] = c0.w * E * F_s[s0 + 3];
            m[4] = c1.x * E * F_s[s0 + 4]; m[5] = c1.y * E * F_s[s0 + 5];
            m[6] = c1.z * E * F_s[s0 + 6]; m[7] = c1.w * E * F_s[s0 + 7];
            if (sb == lb) {
#pragma unroll
                for (int j = 0; j < 8; j++)
                    if (s0 + j > lch[mi]) m[j] = 0.f;
            }
            s16x8 a;
#pragma unroll
            for (int j = 0; j < 8; j++) a[j] = (short)f2bf(m[j]);
#pragma unroll
            for (int ni = 0; ni < 4; ni++)
                acc[mi][ni] = __builtin_amdgcn_mfma_f32_16x16x32_bf16(a, bf[ni], acc[mi][ni], 0, 0, 0);
        }
    }

    const long crow = tbase + ltile * 128 + wm * 64 + ((lane >> 4) << 2);
    const int ccol = h * 128 + wn * 64 + (lane & 15);
#pragma unroll
    for (int mi = 0; mi < 4; mi++)
#pragma unroll
        for (int ni = 0; ni < 4; ni++)
#pragma unroll
            for (int r = 0; r < 4; r++)
                yf[(crow + mi * 16 + r) * 4096 + ccol + ni * 16] = acc[mi][ni][r];
}

// ---------------- per-chunk end states via MFMA ----------------
// grid 512 = bi(2) x cc(8) x h(32); out[p][n] = sum_s (x[s,p]*wl_s) B[s,n]
// A-frag: xT row p scaled by wl; B-frag: Bt row n. K = 256 (8 steps).
__global__ __launch_bounds__(256) void states_mfma_k(const ushort* __restrict__ xT,
                                                     const ushort* __restrict__ Bt,
                                                     const float* __restrict__ dtp,
                                                     const float* __restrict__ dacs,
                                                     float* __restrict__ states) {
    const int bx = blockIdx.x;
    const int h = bx & 31, cc = (bx >> 5) & 7, bi = bx >> 8;
    const int bc = bi * 8 + cc;
    const int tid = threadIdx.x, lane = tid & 63, wave = tid >> 6;
    const int wm = wave >> 1, wn = wave & 1;
    __shared__ float wl[256];
    const long dbase = ((long)(bi * 32 + h)) * 2048 + cc * 256;
    {
        float last = dacs[dbase + 255];
        wl[tid] = __expf(last - dacs[dbase + tid]) * dtp[dbase + tid];
    }
    __syncthreads();

    f32x4 zero = { 0.f, 0.f, 0.f, 0.f };
    f32x4 acc[4][4];
#pragma unroll
    for (int i = 0; i < 4; i++)
#pragma unroll
        for (int j = 0; j < 4; j++) acc[i][j] = zero;

    const ushort* xrow = xT + (((long)bc * 32 + h) * 128) * 256;
    const ushort* brow = Bt + ((long)bc * 128) * 256;

    for (int sb = 0; sb < 8; ++sb) {
        const int soff = sb * 32 + (lane >> 4) * 8;
        s16x8 a[4], b[4];
#pragma unroll
        for (int mi = 0; mi < 4; mi++) {
            int p = wm * 64 + mi * 16 + (lane & 15);
            s16x8 raw = *(const s16x8*)&xrow[(long)p * 256 + soff];
#pragma unroll
            for (int j = 0; j < 8; j++)
                a[mi][j] = (short)f2bf(bf2f((ushort)raw[j]) * wl[soff + j]);
        }
#pragma unroll
        for (int ni = 0; ni < 4; ni++) {
            int n = wn * 64 + ni * 16 + (lane & 15);
            b[ni] = *(const s16x8*)&brow[(long)n * 256 + soff];
        }
#pragma unroll
        for (int mi = 0; mi < 4; mi++)
#pragma unroll
            for (int ni = 0; ni < 4; ni++)
                acc[mi][ni] = __builtin_amdgcn_mfma_f32_16x16x32_bf16(a[mi], b[ni], acc[mi][ni], 0, 0, 0);
    }

    float* out = states + (((long)bc * 32 + h) * 128) * 128;
#pragma unroll
    for (int mi = 0; mi < 4; mi++)
#pragma unroll
        for (int ni = 0; ni < 4; ni++)
#pragma unroll
            for (int r = 0; r < 4; r++) {
                int p = wm * 64 + mi * 16 + (lane >> 4) * 4 + r;
                int n = wn * 64 + ni * 16 + (lane & 15);
                out[(long)p * 128 + n] = acc[mi][ni][r];
            }
}

// ---------------- chunk recurrence: states -> prev_states (in place) ----------------
__global__ void rec_k(float* __restrict__ states, const float* __restrict__ dacs) {
    const int i = blockIdx.x * 256 + threadIdx.x;  // 1,048,576
    const int n = i & 127, p = (i >> 7) & 127, h = (i >> 14) & 31, bi = i >> 19;
    const long dbase = ((long)(bi * 32 + h)) * 2048;
    float run = 0.f;
    for (int cc = 0; cc < 8; cc++) {
        const long off = ((((long)(bi * 8 + cc)) * 32 + h) * 128 + p) * 128 + n;
        float st = states[off];
        states[off] = run;
        float dec = dacs[dbase + cc * 256 + 255];
        run = run * __expf(dec) + st;
    }
}

// ---------------- inter-chunk contribution via MFMA ----------------
// grid 1024 = bi(2) x cc(8) x h(32) x lt(2)
// Y[l,p] += exp(dA_l) * sum_n C[l,n] prev[p,n];  A: C rows (xbcc), B: st rows (f32->bf16).
__global__ __launch_bounds__(256) void inter_mfma_k(const ushort* __restrict__ xbcc,
                                                    const float* __restrict__ st,
                                                    const float* __restrict__ dacs,
                                                    float* __restrict__ yf) {
    const int bx = blockIdx.x;
    const int lt = bx & 1, h = (bx >> 1) & 31, cc = (bx >> 6) & 7, bi = bx >> 9;
    const int tid = threadIdx.x, lane = tid & 63, wave = tid >> 6;
    const int wm = wave >> 1, wn = wave & 1;
    __shared__ float eA[256];
    const long dbase = ((long)(bi * 32 + h)) * 2048 + cc * 256;
    eA[tid] = __expf(dacs[dbase + tid]);
    __syncthreads();

    const long tbase = (long)bi * 2048 + cc * 256;
    const float* sbase = st + (((long)(bi * 8 + cc) * 32 + h) * 128) * 128;

    f32x4 zero = { 0.f, 0.f, 0.f, 0.f };
    f32x4 acc[4][4];
#pragma unroll
    for (int i = 0; i < 4; i++)
#pragma unroll
        for (int j = 0; j < 4; j++) acc[i][j] = zero;

    for (int kk = 0; kk < 4; ++kk) {
        const int koff = kk * 32 + (lane >> 4) * 8;
        s16x8 a[4], b[4];
#pragma unroll
        for (int mi = 0; mi < 4; mi++) {
            int l = lt * 128 + wm * 64 + mi * 16 + (lane & 15);
            a[mi] = *(const s16x8*)&xbcc[(tbase + l) * 4352 + 4224 + koff];
        }
#pragma unroll
        for (int ni = 0; ni < 4; ni++) {
            int p = wn * 64 + ni * 16 + (lane & 15);
            const float* pr = sbase + (long)p * 128 + koff;
            float4 v0 = *(const float4*)pr;
            float4 v1 = *(const float4*)(pr + 4);
            b[ni][0] = (short)f2bf(v0.x); b[ni][1] = (short)f2bf(v0.y);
            b[ni][2] = (short)f2bf(v0.z); b[ni][3] = (short)f2bf(v0.w);
            b[ni][4] = (short)f2bf(v1.x); b[ni][5] = (short)f2bf(v1.y);
            b[ni][6] = (short)f2bf(v1.z); b[ni][7] = (short)f2bf(v1.w);
        }
#pragma unroll
        for (int mi = 0; mi < 4; mi++)
#pragma unroll
            for (int ni = 0; ni < 4; ni++)
                acc[mi][ni] = __builtin_amdgcn_mfma_f32_16x16x32_bf16(a[mi], b[ni], acc[mi][ni], 0, 0, 0);
    }

#pragma unroll
    for (int mi = 0; mi < 4; mi++)
#pragma unroll
        for (int r = 0; r < 4; r++) {
            int l = lt * 128 + wm * 64 + mi * 16 + (lane >> 4) * 4 + r;
            float e = eA[l];
            float* yr = &yf[(tbase + l) * 4096 + h * 128];
#pragma unroll
            for (int ni = 0; ni < 4; ni++) {
                int p = wn * 64 + ni * 16 + (lane & 15);
                yr[p] += e * acc[mi][ni][r];
            }
        }
}

// ---------------- gate (silu(z)) + D*x + RMSNorm -> bf16 ----------------
__global__ __launch_bounds__(256) void gate_rms_k(const float* __restrict__ y, const ushort* __restrict__ zx,
                                                  const ushort* __restrict__ xbcc, const float* __restrict__ Dv,
                                                  const float* __restrict__ norm_w, ushort* __restrict__ yb) {
    const int t = blockIdx.x, tid = threadIdx.x;
    const float* yr = &y[(long)t * 4096];
    const ushort* zr = &zx[(long)t * 8576];
    const ushort* xr = &xbcc[(long)t * 4352];
    float g[16];
    float ss = 0.f;
#pragma unroll
    for (int j = 0; j < 16; j++) {
        int i = j * 256 + tid;
        float z = bf2f(zr[i]);
        float yv = yr[i] + Dv[i >> 7] * bf2f(xr[i]);
        float gv = yv * (z / (1.f + __expf(-z)));
        g[j] = gv;
        ss += gv * gv;
    }
#pragma unroll
    for (int off = 32; off > 0; off >>= 1) ss += __shfl_xor(ss, off, 64);
    __shared__ float red[4];
    if ((tid & 63) == 0) red[tid >> 6] = ss;
    __syncthreads();
    float tot = red[0] + red[1] + red[2] + red[3];
    float sc = rsqrtf(tot * (1.f / 4096.f) + 1e-6f);
#pragma unroll
    for (int j = 0; j < 16; j++) {
        int i = j * 256 + tid;
        yb[(long)t * 4096 + i] = f2bf(g[j] * sc * norm_w[i]);
    }
}

// ---------------------------------------------------------------------------
extern "C" void kernel_launch(void* const* d_in, const int* in_sizes, int n_in,
                              void* d_out, int out_size, void* d_ws, size_t ws_size,
                              hipStream_t stream) {
    const float* x       = (const float*)d_in[0];
    const float* W_in    = (const float*)d_in[1];
    const float* conv_w  = (const float*)d_in[2];
    const float* conv_b  = (const float*)d_in[3];
    const float* dt_bias = (const float*)d_in[4];
    const float* A_log   = (const float*)d_in[5];
    const float* Dv      = (const float*)d_in[6];
    const float* norm_w  = (const float*)d_in[7];
    const float* W_out   = (const float*)d_in[8];

    char* w8 = (char*)d_ws;
    ushort* xb    = (ushort*)(w8 + 0L);
    ushort* xT    = (ushort*)(w8 + 0L);           // alias (xb/winb dead after GEMM1)
    ushort* yb    = (ushort*)(w8 + 0L);           // alias (xT dead after states/intra)
    ushort* winb  = (ushort*)(w8 + 16777216L);
    ushort* woutb = (ushort*)(w8 + 33554432L);    // alias (winb dead after GEMM1)
    ushort* Bt    = (ushort*)(w8 + 50331648L);
    ushort* zx    = (ushort*)(w8 + 51904512L);
    ushort* xbcc  = (ushort*)(w8 + 122159104L);
    float*  dtp   = (float*)(w8 + 157810688L);
    float*  dacs  = (float*)(w8 + 158334976L);
    float*  cb    = (float*)(w8 + 158859264L);
    float*  yf    = (float*)(w8 + 163053568L);
    float*  st    = (float*)(w8 + 230162432L);

    cast4_k<<<8192, 256, 0, stream>>>((const float4*)x, xb, 2097152L);
    cast_win_k<<<17152, 256, 0, stream>>>((const float4*)W_in, winb);
    gemm_bt_k<1><<<2144, 256, 0, stream>>>(xb, winb, (void*)zx, 8576, 2048);
    cast4_k<<<8192, 256, 0, stream>>>((const float4*)W_out, woutb, 2097152L);
    conv_silu_k<<<69632, 256, 0, stream>>>(zx, conv_w, conv_b, xbcc);
    prep_k<<<512, 64, 0, stream>>>(zx, dt_bias, A_log, dtp, dacs);
    xpose_k<<<dim3(8, 33, 16), 256, 0, stream>>>(xbcc, xT, Bt);
    cb_k<<<128, 256, 0, stream>>>(xbcc, cb);
    intra_mfma_k<<<1024, 256, 0, stream>>>(xT, cb, dtp, dacs, yf);
    states_mfma_k<<<512, 256, 0, stream>>>(xT, Bt, dtp, dacs, st);
    rec_k<<<4096, 256, 0, stream>>>(st, dacs);
    inter_mfma_k<<<1024, 256, 0, stream>>>(xbcc, st, dacs, yf);
    gate_rms_k<<<4096, 256, 0, stream>>>(yf, zx, xbcc, Dv, norm_w, yb);
    gemm_bt_k<0><<<512, 256, 0, stream>>>(yb, woutb, d_out, 2048, 4096);
}